// Round 11
// baseline (1919.239 us; speedup 1.0000x reference)
//
#include <hip/hip_runtime.h>
#include <hip/hip_bf16.h>

#define DM 256
#define NH 8
#define DK 32
#define BSZ 2
#define SEQ 2048
#define ROWS (BSZ*SEQ)   // 4096
#define RT 8             // query rows per attention tile
#define SROW 2304        // phys row stride; swizzle phys = j + 4*(j>>5), max 2299

static __device__ __forceinline__ int sw(int j) { return j + ((j >> 5) << 2); }

// ---------- block reduction helpers (256 threads = 4 waves) ----------
static __device__ __forceinline__ float waveRedSum(float v) {
    #pragma unroll
    for (int off = 32; off > 0; off >>= 1) v += __shfl_down(v, off, 64);
    return v;
}
static __device__ __forceinline__ float blockRedSum(float v, float* red) {
    int lane = threadIdx.x & 63, wid = threadIdx.x >> 6;
    v = waveRedSum(v);
    __syncthreads();
    if (lane == 0) red[wid] = v;
    __syncthreads();
    return red[0] + red[1] + red[2] + red[3];
}

// ---------- batched GEMM: up to 4 sets of Y = X@W + b, W-pipelined ----------
__global__ __launch_bounds__(256) void gemm4_kernel(
    const float* __restrict__ X0, const float* __restrict__ W0, const float* __restrict__ B0, float* __restrict__ Y0,
    const float* __restrict__ X1, const float* __restrict__ W1, const float* __restrict__ B1, float* __restrict__ Y1,
    const float* __restrict__ X2, const float* __restrict__ W2, const float* __restrict__ B2, float* __restrict__ Y2,
    const float* __restrict__ X3, const float* __restrict__ W3, const float* __restrict__ B3, float* __restrict__ Y3)
{
    const float *X, *W, *Bb; float* Y;
    int s = blockIdx.y;
    if (s == 0)      { X = X0; W = W0; Bb = B0; Y = Y0; }
    else if (s == 1) { X = X1; W = W1; Bb = B1; Y = Y1; }
    else if (s == 2) { X = X2; W = W2; Bb = B2; Y = Y2; }
    else             { X = X3; W = W3; Bb = B3; Y = Y3; }

    __shared__ float xl[16][DM];
    int t = threadIdx.x;
    int r0 = blockIdx.x * 16;
    #pragma unroll 4
    for (int k = 0; k < 16; ++k) xl[k][t] = X[(size_t)(r0 + k) * DM + t];
    __syncthreads();
    float acc[16];
    #pragma unroll
    for (int r = 0; r < 16; ++r) acc[r] = 0.f;
    float w0 = W[t], w1 = W[DM + t], w2 = W[2 * DM + t], w3 = W[3 * DM + t];
    #pragma unroll 1
    for (int k = 0; k < DM; k += 4) {
        float c0 = w0, c1 = w1, c2 = w2, c3 = w3;
        if (k + 4 < DM) {
            w0 = W[(size_t)(k + 4) * DM + t];
            w1 = W[(size_t)(k + 5) * DM + t];
            w2 = W[(size_t)(k + 6) * DM + t];
            w3 = W[(size_t)(k + 7) * DM + t];
        }
        #pragma unroll
        for (int r = 0; r < 16; ++r) {
            float4 xv = *(const float4*)&xl[r][k];
            acc[r] += xv.x * c0 + xv.y * c1 + xv.z * c2 + xv.w * c3;
        }
    }
    float bb = Bb[t];
    #pragma unroll 4
    for (int r = 0; r < 16; ++r) Y[(size_t)(r0 + r) * DM + t] = acc[r] + bb;
}

// ---------- GEMM + residual + LayerNorm fused (up to 2 sets), W-pipelined ---
__global__ __launch_bounds__(256) void gemm_ln2_kernel(
    const float* __restrict__ X0, const float* __restrict__ W0, const float* __restrict__ B0,
    const float* __restrict__ R0, const float* __restrict__ G0, const float* __restrict__ L0,
    float* __restrict__ Y0, int bc0,
    const float* __restrict__ X1, const float* __restrict__ W1, const float* __restrict__ B1,
    const float* __restrict__ R1, const float* __restrict__ G1, const float* __restrict__ L1,
    float* __restrict__ Y1, int bc1)
{
    const float *X, *W, *Bb, *R, *G, *L; float* Y; int bc;
    if (blockIdx.y == 0) { X=X0; W=W0; Bb=B0; R=R0; G=G0; L=L0; Y=Y0; bc=bc0; }
    else                 { X=X1; W=W1; Bb=B1; R=R1; G=G1; L=L1; Y=Y1; bc=bc1; }

    __shared__ float xl[16][DM];
    __shared__ float mn[16], rv[16];
    int t = threadIdx.x;
    int r0 = blockIdx.x * 16;
    #pragma unroll 4
    for (int k = 0; k < 16; ++k) xl[k][t] = X[(size_t)(r0 + k) * DM + t];
    __syncthreads();
    float acc[16];
    #pragma unroll
    for (int r = 0; r < 16; ++r) acc[r] = 0.f;
    float w0 = W[t], w1 = W[DM + t], w2 = W[2 * DM + t], w3 = W[3 * DM + t];
    #pragma unroll 1
    for (int k = 0; k < DM; k += 4) {
        float c0 = w0, c1 = w1, c2 = w2, c3 = w3;
        if (k + 4 < DM) {
            w0 = W[(size_t)(k + 4) * DM + t];
            w1 = W[(size_t)(k + 5) * DM + t];
            w2 = W[(size_t)(k + 6) * DM + t];
            w3 = W[(size_t)(k + 7) * DM + t];
        }
        #pragma unroll
        for (int r = 0; r < 16; ++r) {
            float4 xv = *(const float4*)&xl[r][k];
            acc[r] += xv.x * c0 + xv.y * c1 + xv.z * c2 + xv.w * c3;
        }
    }
    float bb = Bb[t];
    __syncthreads();          // all readers of xl done before overwrite
    #pragma unroll 4
    for (int r = 0; r < 16; ++r) {
        float res = bc ? R[t] : R[(size_t)(r0 + r) * DM + t];
        xl[r][t] = acc[r] + bb + res;
    }
    __syncthreads();
    {   // 16 threads per row: mean & var
        int r = t >> 4, l16 = t & 15;
        float part = 0.f;
        #pragma unroll
        for (int c = 0; c < 16; ++c) part += xl[r][l16 * 16 + c];
        #pragma unroll
        for (int off = 8; off; off >>= 1) part += __shfl_xor(part, off, 16);
        float mean = part * (1.f / DM);
        float vp = 0.f;
        #pragma unroll
        for (int c = 0; c < 16; ++c) {
            float d = xl[r][l16 * 16 + c] - mean;
            vp += d * d;
        }
        #pragma unroll
        for (int off = 8; off; off >>= 1) vp += __shfl_xor(vp, off, 16);
        if (l16 == 0) { mn[r] = mean; rv[r] = rsqrtf(vp * (1.f / DM) + 1e-5f); }
    }
    __syncthreads();
    float gg = G[t], ll = L[t];
    #pragma unroll 4
    for (int r = 0; r < 16; ++r)
        Y[(size_t)(r0 + r) * DM + t] = (xl[r][t] - mn[r]) * rv[r] * gg + ll;
}

// ---------- tiled attention with distance-decay bias ----------
// RT=8, dual-set (blockIdx.y>>4), largest-first. K rows preloaded into
// registers (pipelined); qs kept in LDS via per-q clobber (r6/r7 LICM spills).
__global__ __launch_bounds__(256, 2) void attn_tile_kernel(
    const float* __restrict__ Q0, const float* __restrict__ K0, const float* __restrict__ V0,
    const float* __restrict__ g0, float* __restrict__ O0,
    const float* __restrict__ Q1, const float* __restrict__ K1, const float* __restrict__ V1,
    const float* __restrict__ g1, float* __restrict__ O1,
    int peek, int qbcast)
{
    __shared__ __align__(16) float S[RT * SROW];
    __shared__ float qs[RT][DK];
    __shared__ float l2inv_s[RT];

    int y = blockIdx.y;
    int set = y >> 4, bh = y & 15;
    const float* Q = set ? Q1 : Q0;
    const float* K = set ? K1 : K0;
    const float* V = set ? V1 : V0;
    const float* gm = set ? g1 : g0;
    float* O = set ? O1 : O0;

    int b = bh >> 3, h = bh & 7;
    int i0 = ((int)gridDim.x - 1 - (int)blockIdx.x) * RT;   // largest-first
    int t = threadIdx.x;
    size_t base = ((size_t)b * SEQ) * DM + (size_t)h * DK;

    {   // load Q tile
        int r = t >> 5, d = t & 31;
        if (t < RT * DK)
            qs[r][d] = qbcast ? Q[(size_t)h * DK + d]
                              : Q[base + (size_t)(i0 + r) * DM + d];
    }
    __syncthreads();

    int njAll = peek ? (i0 + RT) : (i0 + RT - 1);  // >= 7 always
    int njPad = (njAll + 3) & ~3;
    const float scale = 0.17677669529663687f;      // 1/sqrt(32)

    // ---- Phase 1: scores. 4 K rows preloaded to regs, q-loop unrolled.
    #pragma unroll 1
    for (int jb = t; jb < njAll; jb += 1024) {
        int j1 = jb + 256, j2 = jb + 512, j3 = jb + 768;
        int c1 = j1 < njAll ? j1 : jb;
        int c2 = j2 < njAll ? j2 : jb;
        int c3 = j3 < njAll ? j3 : jb;
        const float4* kp0 = (const float4*)(K + base + (size_t)jb * DM);
        const float4* kp1 = (const float4*)(K + base + (size_t)c1 * DM);
        const float4* kp2 = (const float4*)(K + base + (size_t)c2 * DM);
        const float4* kp3 = (const float4*)(K + base + (size_t)c3 * DM);
        float4 k0[8], k1[8], k2[8], k3[8];
        #pragma unroll
        for (int q = 0; q < 8; ++q) {
            k0[q] = kp0[q]; k1[q] = kp1[q]; k2[q] = kp2[q]; k3[q] = kp3[q];
        }
        float s0[RT], s1[RT], s2[RT], s3[RT];
        #pragma unroll
        for (int r = 0; r < RT; ++r) { s0[r]=0.f; s1[r]=0.f; s2[r]=0.f; s3[r]=0.f; }
        #pragma unroll
        for (int q = 0; q < 8; ++q) {
            #pragma unroll
            for (int r = 0; r < RT; ++r) {
                float4 qv = *(const float4*)&qs[r][4 * q];
                s0[r] += qv.x*k0[q].x + qv.y*k0[q].y + qv.z*k0[q].z + qv.w*k0[q].w;
                s1[r] += qv.x*k1[q].x + qv.y*k1[q].y + qv.z*k1[q].z + qv.w*k1[q].w;
                s2[r] += qv.x*k2[q].x + qv.y*k2[q].y + qv.z*k2[q].z + qv.w*k2[q].w;
                s3[r] += qv.x*k3[q].x + qv.y*k3[q].y + qv.z*k3[q].z + qv.w*k3[q].w;
            }
            asm volatile("" ::: "memory");   // qs stays in LDS (anti-LICM)
        }
        {
            int sj = sw(jb);
            #pragma unroll
            for (int r = 0; r < RT; ++r) S[r * SROW + sj] = s0[r] * scale;
        }
        if (j1 < njAll) { int sj = sw(j1);
            #pragma unroll
            for (int r = 0; r < RT; ++r) S[r * SROW + sj] = s1[r] * scale; }
        if (j2 < njAll) { int sj = sw(j2);
            #pragma unroll
            for (int r = 0; r < RT; ++r) S[r * SROW + sj] = s2[r] * scale; }
        if (j3 < njAll) { int sj = sw(j3);
            #pragma unroll
            for (int r = 0; r < RT; ++r) S[r * SROW + sj] = s3[r] * scale; }
    }
    __syncthreads();

    // ---- Phases 2-4: per row, 32 lanes, quad-interleaved
    {
        int r = t >> 5, c = t & 31;
        int i = i0 + r;
        int nj = peek ? (i + 1) : i;          // may be 0 (attn3 row 0)
        float* Sr = S + r * SROW;
        float gamma = -log1pf(__expf(gm[h]));    // -softplus

        // A: max
        float m = -1e30f;
        #pragma unroll 1
        for (int j4 = 4 * c; j4 < nj; j4 += 128) {
            float4 s4 = *(const float4*)&Sr[sw(j4)];
            if (j4 + 0 < nj) m = fmaxf(m, s4.x);
            if (j4 + 1 < nj) m = fmaxf(m, s4.y);
            if (j4 + 2 < nj) m = fmaxf(m, s4.z);
            if (j4 + 3 < nj) m = fmaxf(m, s4.w);
        }
        #pragma unroll
        for (int off = 16; off; off >>= 1) m = fmaxf(m, __shfl_xor(m, off, 32));

        // B: sum exp
        float l = 0.f;
        #pragma unroll 1
        for (int j4 = 4 * c; j4 < nj; j4 += 128) {
            float4 s4 = *(const float4*)&Sr[sw(j4)];
            if (j4 + 0 < nj) l += __expf(s4.x - m);
            if (j4 + 1 < nj) l += __expf(s4.y - m);
            if (j4 + 2 < nj) l += __expf(s4.z - m);
            if (j4 + 3 < nj) l += __expf(s4.w - m);
        }
        #pragma unroll
        for (int off = 16; off; off >>= 1) l += __shfl_xor(l, off, 32);
        float linv = 1.f / l;

        // C: ordered cumsum + decay bias (k-stepped 32-lane scan)
        float m2 = -1e30f;
        float Bc = 0.f;
        #pragma unroll 1
        for (int k = 0; 128 * k < nj; ++k) {
            int j4 = 128 * k + 4 * c;                 // <= 2044: in-bounds read
            float4 s4 = *(const float4*)&Sr[sw(j4)];
            bool v0 = j4 + 0 < nj, v1 = j4 + 1 < nj, v2 = j4 + 2 < nj, v3 = j4 + 3 < nj;
            float e0 = v0 ? __expf(s4.x - m) * linv : 0.f;
            float e1 = v1 ? __expf(s4.y - m) * linv : 0.f;
            float e2 = v2 ? __expf(s4.z - m) * linv : 0.f;
            float e3 = v3 ? __expf(s4.w - m) * linv : 0.f;
            float sig = e0 + e1 + e2 + e3;
            float x = sig;
            #pragma unroll
            for (int off = 1; off < 32; off <<= 1) {
                float yv = __shfl_up(x, off, 32);
                if (c >= off) x += yv;
            }
            float tot = __shfl(x, 31, 32);
            float cum = Bc + (x - sig);
            Bc += tot;
            cum += e0;
            if (v0) { float dist = sqrtf(fmaxf((1.f - cum) * (float)(i - j4 - 0), 0.f));
                      float eff = fminf(fmaxf(__expf(dist * gamma), 1e-5f), 1e5f);
                      s4.x *= eff; m2 = fmaxf(m2, s4.x); } else s4.x = -1e30f;
            cum += e1;
            if (v1) { float dist = sqrtf(fmaxf((1.f - cum) * (float)(i - j4 - 1), 0.f));
                      float eff = fminf(fmaxf(__expf(dist * gamma), 1e-5f), 1e5f);
                      s4.y *= eff; m2 = fmaxf(m2, s4.y); } else s4.y = -1e30f;
            cum += e2;
            if (v2) { float dist = sqrtf(fmaxf((1.f - cum) * (float)(i - j4 - 2), 0.f));
                      float eff = fminf(fmaxf(__expf(dist * gamma), 1e-5f), 1e5f);
                      s4.z *= eff; m2 = fmaxf(m2, s4.z); } else s4.z = -1e30f;
            cum += e3;
            if (v3) { float dist = sqrtf(fmaxf((1.f - cum) * (float)(i - j4 - 3), 0.f));
                      float eff = fminf(fmaxf(__expf(dist * gamma), 1e-5f), 1e5f);
                      s4.w *= eff; m2 = fmaxf(m2, s4.w); } else s4.w = -1e30f;
            *(float4*)&Sr[sw(j4)] = s4;
        }
        #pragma unroll
        for (int off = 16; off; off >>= 1) m2 = fmaxf(m2, __shfl_xor(m2, off, 32));

        // D: p = exp(s2-m2), zero-fill [nj, njPad), sum l2
        float l2 = 0.f;
        #pragma unroll 1
        for (int j4 = 4 * c; j4 < njPad; j4 += 128) {
            float4 s4 = *(const float4*)&Sr[sw(j4)];
            float4 p;
            p.x = (j4 + 0 < nj) ? __expf(s4.x - m2) : 0.f;
            p.y = (j4 + 1 < nj) ? __expf(s4.y - m2) : 0.f;
            p.z = (j4 + 2 < nj) ? __expf(s4.z - m2) : 0.f;
            p.w = (j4 + 3 < nj) ? __expf(s4.w - m2) : 0.f;
            l2 += p.x + p.y + p.z + p.w;
            *(float4*)&Sr[sw(j4)] = p;
        }
        #pragma unroll
        for (int off = 16; off; off >>= 1) l2 += __shfl_xor(l2, off, 32);
        if (c == 0) l2inv_s[r] = (nj > 0) ? (1.f / l2) : 0.f;
    }
    __syncthreads();

    // ---- Phase 5 PV: thread=(jg,d); V loads pipelined 1 iter ahead
    {
        int d = t & 31, jg = t >> 5;
        float acc[RT];
        #pragma unroll
        for (int r = 0; r < RT; ++r) acc[r] = 0.f;
        int j0 = jg * 4;
        float nv0 = 0.f, nv1 = 0.f, nv2 = 0.f, nv3 = 0.f;
        if (j0 < njPad) {
            nv0 = V[base + (size_t)(j0 + 0) * DM + d];
            nv1 = V[base + (size_t)(j0 + 1) * DM + d];
            nv2 = V[base + (size_t)(j0 + 2) * DM + d];
            nv3 = V[base + (size_t)(j0 + 3) * DM + d];
        }
        #pragma unroll 1
        for (int j = j0; j < njPad; j += 32) {
            float v0 = nv0, v1 = nv1, v2 = nv2, v3 = nv3;
            int jn = j + 32;
            if (jn < njPad) {
                nv0 = V[base + (size_t)(jn + 0) * DM + d];
                nv1 = V[base + (size_t)(jn + 1) * DM + d];
                nv2 = V[base + (size_t)(jn + 2) * DM + d];
                nv3 = V[base + (size_t)(jn + 3) * DM + d];
            }
            int sj = sw(j);
            #pragma unroll
            for (int r = 0; r < RT; ++r) {
                float4 p = *(const float4*)&S[r * SROW + sj];
                acc[r] += p.x * v0 + p.y * v1 + p.z * v2 + p.w * v3;
            }
        }
        __syncthreads();          // done reading S -> reuse as scratch
        #pragma unroll
        for (int r = 0; r < RT; ++r)
            S[(jg * RT + r) * 32 + d] = acc[r];    // [jg][r][d]
    }
    __syncthreads();
    {
        int r2 = t >> 5, d = t & 31;
        float sum = 0.f;
        #pragma unroll
        for (int jg = 0; jg < 8; ++jg)
            sum += S[(jg * RT + r2) * 32 + d];
        int ii = i0 + r2;
        int njr = peek ? (ii + 1) : ii;
        O[base + (size_t)ii * DM + d] = (njr > 0) ? sum * l2inv_s[r2] : 0.f;
    }
}

// ---------- small precompute: q3row = know@W3q+b3q; key8 = sigmoid heads ---
__global__ __launch_bounds__(256) void precompute_kernel(
    const float* __restrict__ know,
    const float* __restrict__ W3q, const float* __restrict__ b3q,
    const float* __restrict__ lkW, const float* __restrict__ lkb,
    float* __restrict__ q3row, float* __restrict__ key8)
{
    __shared__ float kn[DM];
    int t = threadIdx.x;
    kn[t] = know[t];
    __syncthreads();
    float acc = b3q[t];
    for (int c = 0; c < DM; ++c) acc += kn[c] * W3q[(size_t)c * DM + t];
    q3row[t] = acc;
    float bk = lkb[t];
    for (int h = 0; h < NH; ++h) {
        float a = bk;
        #pragma unroll
        for (int c = 0; c < DK; ++c) a += kn[h * DK + c] * lkW[(size_t)c * DM + t];
        key8[(size_t)h * DM + t] = 1.f / (1.f + __expf(-a));
    }
}

// ---------- final readout (f32 output) ----------
__global__ __launch_bounds__(256) void readout_kernel(
    const float* __restrict__ h3, const float* __restrict__ qe,
    const float* __restrict__ key8,
    const float* __restrict__ lvW, const float* __restrict__ lvb,
    float* __restrict__ out)
{
    __shared__ float hrow[DM], qrow[DM];
    __shared__ float red[4];
    int n = blockIdx.x, t = threadIdx.x;
    hrow[t] = h3[(size_t)n * DM + t];
    qrow[t] = qe[(size_t)n * DM + t];
    __syncthreads();
    float beta[NH];
    for (int h = 0; h < NH; ++h)
        beta[h] = blockRedSum(key8[(size_t)h * DM + t] * qrow[t], red);
    float bv = lvb[t];
    float vh[NH];
    for (int h = 0; h < NH; ++h) {
        float a = bv;
        #pragma unroll
        for (int c = 0; c < DK; ++c) a += hrow[h * DK + c] * lvW[(size_t)c * DM + t];
        vh[h] = 1.f / (1.f + __expf(-a));
    }
    float mb = beta[0];
    #pragma unroll
    for (int h = 1; h < NH; ++h) mb = fmaxf(mb, beta[h]);
    float se = 0.f, eh[NH];
    #pragma unroll
    for (int h = 0; h < NH; ++h) { eh[h] = __expf(beta[h] - mb); se += eh[h]; }
    float sinv = 1.f / se;
    float o = 0.f;
    #pragma unroll
    for (int h = 0; h < NH; ++h) o += eh[h] * sinv * vh[h];
    out[(size_t)n * DM + t] = o;
}

extern "C" void kernel_launch(void* const* d_in, const int* in_sizes, int n_in,
                              void* d_out, int out_size, void* d_ws, size_t ws_size,
                              hipStream_t stream) {
    (void)in_sizes; (void)n_in; (void)out_size; (void)ws_size;
    const float* q_emb  = (const float*)d_in[0];
    const float* qa_emb = (const float*)d_in[1];
    const float* b1_Wq = (const float*)d_in[2];
    const float* b1_bq = (const float*)d_in[3];
    const float* b1_Wv = (const float*)d_in[4];
    const float* b1_bv = (const float*)d_in[5];
    const float* b1_Wo = (const float*)d_in[6];
    const float* b1_bo = (const float*)d_in[7];
    const float* b1_gam = (const float*)d_in[8];
    const float* b1_lng = (const float*)d_in[9];
    const float* b1_lnb = (const float*)d_in[10];
    const float* b2_Wq = (const float*)d_in[11];
    const float* b2_bq = (const float*)d_in[12];
    const float* b2_Wv = (const float*)d_in[13];
    const float* b2_bv = (const float*)d_in[14];
    const float* b2_Wo = (const float*)d_in[15];
    const float* b2_bo = (const float*)d_in[16];
    const float* b2_gam = (const float*)d_in[17];
    const float* b2_lng = (const float*)d_in[18];
    const float* b2_lnb = (const float*)d_in[19];
    const float* b3_Wq = (const float*)d_in[20];
    const float* b3_bq = (const float*)d_in[21];
    const float* b3_Wk = (const float*)d_in[22];
    const float* b3_bk = (const float*)d_in[23];
    const float* b3_Wv = (const float*)d_in[24];
    const float* b3_bv = (const float*)d_in[25];
    const float* b3_Wo = (const float*)d_in[26];
    const float* b3_bo = (const float*)d_in[27];
    const float* b3_gam = (const float*)d_in[28];
    const float* b3_lng = (const float*)d_in[29];
    const float* b3_lnb = (const float*)d_in[30];
    const float* know  = (const float*)d_in[31];
    const float* lk_W  = (const float*)d_in[32];
    const float* lk_b  = (const float*)d_in[33];
    const float* lv_W  = (const float*)d_in[34];
    const float* lv_b  = (const float*)d_in[35];

    const size_t SLAB = (size_t)ROWS * DM;  // 1,048,576 floats = 4 MB
    float* A1 = (float*)d_ws;
    float* B1 = A1 + SLAB;
    float* A2 = B1 + SLAB;
    float* B2 = A2 + SLAB;
    float* C1 = B2 + SLAB;
    float* C2 = C1 + SLAB;
    float* q3row = C2 + SLAB;         // 256
    float* key8  = q3row + DM;        // 8*256

    dim3 blk(256);
    dim3 agrid2(SEQ / RT, 32);        // dual-set attention
    dim3 agrid1(SEQ / RT, 16);        // single-set attention
    dim3 rgrid(ROWS);

    precompute_kernel<<<dim3(1), blk, 0, stream>>>(know, b3_Wq, b3_bq, lk_W, lk_b, q3row, key8);

    // ---- blocks 1+2 QKV projections (4 GEMMs, one launch) ----
    gemm4_kernel<<<dim3(ROWS/16, 4), blk, 0, stream>>>(
        q_emb,  b1_Wq, b1_bq, A1,
        q_emb,  b1_Wv, b1_bv, B1,
        qa_emb, b2_Wq, b2_bq, A2,
        qa_emb, b2_Wv, b2_bv, B2);

    // ---- blocks 1+2 attention (one dual-set launch) ----
    attn_tile_kernel<<<agrid2, blk, 0, stream>>>(
        A1, A1, B1, b1_gam, C1,
        A2, A2, B2, b2_gam, C2, 1, 0);

    // ---- output projections + residual + LN (fused) -> hq, ha ----
    gemm_ln2_kernel<<<dim3(ROWS/16, 2), blk, 0, stream>>>(
        C1, b1_Wo, b1_bo, q_emb,  b1_lng, b1_lnb, B1, 0,
        C2, b2_Wo, b2_bo, qa_emb, b2_lng, b2_lnb, B2, 0);

    // ---- block 3: k3 = hq@W3k, v3 = ha@W3v ----
    gemm4_kernel<<<dim3(ROWS/16, 2), blk, 0, stream>>>(
        B1, b3_Wk, b3_bk, A1,
        B2, b3_Wv, b3_bv, A2,
        B1, b3_Wk, b3_bk, A1,   // unused
        B1, b3_Wk, b3_bk, A1);

    attn_tile_kernel<<<agrid1, blk, 0, stream>>>(
        q3row, A1, A2, b3_gam, C1,
        q3row, A1, A2, b3_gam, C1, 0, 1);

    // ---- y3 + know-residual + LN (fused) -> h3 ----
    gemm_ln2_kernel<<<dim3(ROWS/16, 1), blk, 0, stream>>>(
        C1, b3_Wo, b3_bo, know, b3_lng, b3_lnb, A1, 1,
        C1, b3_Wo, b3_bo, know, b3_lng, b3_lnb, A1, 1);

    readout_kernel<<<rgrid, blk, 0, stream>>>(A1, q_emb, key8, lv_W, lv_b,
                                              (float*)d_out);
}

// Round 12
// 1115.628 us; speedup vs baseline: 1.7203x; 1.7203x over previous
//
#include <hip/hip_runtime.h>
#include <hip/hip_bf16.h>

#define DM 256
#define NH 8
#define DK 32
#define BSZ 2
#define SEQ 2048
#define ROWS (BSZ*SEQ)   // 4096
#define RT 8             // query rows per attention tile
#define SROW 2304        // phys row stride; swizzle phys = j + 4*(j>>5), max 2299
#define GR 8             // gemm rows per block

static __device__ __forceinline__ int sw(int j) { return j + ((j >> 5) << 2); }

// ---------- block reduction helpers (256 threads = 4 waves) ----------
static __device__ __forceinline__ float waveRedSum(float v) {
    #pragma unroll
    for (int off = 32; off > 0; off >>= 1) v += __shfl_down(v, off, 64);
    return v;
}
static __device__ __forceinline__ float blockRedSum(float v, float* red) {
    int lane = threadIdx.x & 63, wid = threadIdx.x >> 6;
    v = waveRedSum(v);
    __syncthreads();
    if (lane == 0) red[wid] = v;
    __syncthreads();
    return red[0] + red[1] + red[2] + red[3];
}

// ---------- batched GEMM: up to 4 sets, 8 rows/block, W-pipelined ----------
__global__ __launch_bounds__(256) void gemm4_kernel(
    const float* __restrict__ X0, const float* __restrict__ W0, const float* __restrict__ B0, float* __restrict__ Y0,
    const float* __restrict__ X1, const float* __restrict__ W1, const float* __restrict__ B1, float* __restrict__ Y1,
    const float* __restrict__ X2, const float* __restrict__ W2, const float* __restrict__ B2, float* __restrict__ Y2,
    const float* __restrict__ X3, const float* __restrict__ W3, const float* __restrict__ B3, float* __restrict__ Y3)
{
    const float *X, *W, *Bb; float* Y;
    int s = blockIdx.y;
    if (s == 0)      { X = X0; W = W0; Bb = B0; Y = Y0; }
    else if (s == 1) { X = X1; W = W1; Bb = B1; Y = Y1; }
    else if (s == 2) { X = X2; W = W2; Bb = B2; Y = Y2; }
    else             { X = X3; W = W3; Bb = B3; Y = Y3; }

    __shared__ float xl[GR][DM];
    int t = threadIdx.x;
    int r0 = blockIdx.x * GR;
    #pragma unroll
    for (int k = 0; k < GR; ++k) xl[k][t] = X[(size_t)(r0 + k) * DM + t];
    __syncthreads();
    float acc[GR];
    #pragma unroll
    for (int r = 0; r < GR; ++r) acc[r] = 0.f;
    float w0 = W[t], w1 = W[DM + t], w2 = W[2 * DM + t], w3 = W[3 * DM + t];
    #pragma unroll 1
    for (int k = 0; k < DM; k += 4) {
        float c0 = w0, c1 = w1, c2 = w2, c3 = w3;
        if (k + 4 < DM) {
            w0 = W[(size_t)(k + 4) * DM + t];
            w1 = W[(size_t)(k + 5) * DM + t];
            w2 = W[(size_t)(k + 6) * DM + t];
            w3 = W[(size_t)(k + 7) * DM + t];
        }
        #pragma unroll
        for (int r = 0; r < GR; ++r) {
            float4 xv = *(const float4*)&xl[r][k];
            acc[r] += xv.x * c0 + xv.y * c1 + xv.z * c2 + xv.w * c3;
        }
    }
    float bb = Bb[t];
    #pragma unroll
    for (int r = 0; r < GR; ++r) Y[(size_t)(r0 + r) * DM + t] = acc[r] + bb;
}

// ---------- GEMM + residual + LayerNorm fused (2 sets), 8 rows/block -------
__global__ __launch_bounds__(256) void gemm_ln2_kernel(
    const float* __restrict__ X0, const float* __restrict__ W0, const float* __restrict__ B0,
    const float* __restrict__ R0, const float* __restrict__ G0, const float* __restrict__ L0,
    float* __restrict__ Y0, int bc0,
    const float* __restrict__ X1, const float* __restrict__ W1, const float* __restrict__ B1,
    const float* __restrict__ R1, const float* __restrict__ G1, const float* __restrict__ L1,
    float* __restrict__ Y1, int bc1)
{
    const float *X, *W, *Bb, *R, *G, *L; float* Y; int bc;
    if (blockIdx.y == 0) { X=X0; W=W0; Bb=B0; R=R0; G=G0; L=L0; Y=Y0; bc=bc0; }
    else                 { X=X1; W=W1; Bb=B1; R=R1; G=G1; L=L1; Y=Y1; bc=bc1; }

    __shared__ float xl[GR][DM];
    __shared__ float mn[GR], rv[GR];
    int t = threadIdx.x;
    int r0 = blockIdx.x * GR;
    #pragma unroll
    for (int k = 0; k < GR; ++k) xl[k][t] = X[(size_t)(r0 + k) * DM + t];
    __syncthreads();
    float acc[GR];
    #pragma unroll
    for (int r = 0; r < GR; ++r) acc[r] = 0.f;
    float w0 = W[t], w1 = W[DM + t], w2 = W[2 * DM + t], w3 = W[3 * DM + t];
    #pragma unroll 1
    for (int k = 0; k < DM; k += 4) {
        float c0 = w0, c1 = w1, c2 = w2, c3 = w3;
        if (k + 4 < DM) {
            w0 = W[(size_t)(k + 4) * DM + t];
            w1 = W[(size_t)(k + 5) * DM + t];
            w2 = W[(size_t)(k + 6) * DM + t];
            w3 = W[(size_t)(k + 7) * DM + t];
        }
        #pragma unroll
        for (int r = 0; r < GR; ++r) {
            float4 xv = *(const float4*)&xl[r][k];
            acc[r] += xv.x * c0 + xv.y * c1 + xv.z * c2 + xv.w * c3;
        }
    }
    float bb = Bb[t];
    __syncthreads();          // all readers of xl done before overwrite
    #pragma unroll
    for (int r = 0; r < GR; ++r) {
        float res = bc ? R[t] : R[(size_t)(r0 + r) * DM + t];
        xl[r][t] = acc[r] + bb + res;
    }
    __syncthreads();
    {   // 32 threads per row: mean & var
        int r = t >> 5, c32 = t & 31;
        float part = 0.f;
        #pragma unroll
        for (int c = 0; c < 8; ++c) part += xl[r][c32 * 8 + c];
        #pragma unroll
        for (int off = 16; off; off >>= 1) part += __shfl_xor(part, off, 32);
        float mean = part * (1.f / DM);
        float vp = 0.f;
        #pragma unroll
        for (int c = 0; c < 8; ++c) {
            float d = xl[r][c32 * 8 + c] - mean;
            vp += d * d;
        }
        #pragma unroll
        for (int off = 16; off; off >>= 1) vp += __shfl_xor(vp, off, 32);
        if (c32 == 0) { mn[r] = mean; rv[r] = rsqrtf(vp * (1.f / DM) + 1e-5f); }
    }
    __syncthreads();
    float gg = G[t], ll = L[t];
    #pragma unroll
    for (int r = 0; r < GR; ++r)
        Y[(size_t)(r0 + r) * DM + t] = (xl[r][t] - mn[r]) * rv[r] * gg + ll;
}

// ---------- tiled attention with distance-decay bias ----------
// RT=8, dual-set (blockIdx.y>>4), largest-first. Phase-1 q-loop is 1-deep
// double-buffered (c/n regs); qs stays in LDS via clobber. VGPR budget must
// stay <=~128: full K preload (r11) spilled 1.35GB and doubled runtime.
__global__ __launch_bounds__(256) void attn_tile_kernel(
    const float* __restrict__ Q0, const float* __restrict__ K0, const float* __restrict__ V0,
    const float* __restrict__ g0, float* __restrict__ O0,
    const float* __restrict__ Q1, const float* __restrict__ K1, const float* __restrict__ V1,
    const float* __restrict__ g1, float* __restrict__ O1,
    int peek, int qbcast)
{
    __shared__ __align__(16) float S[RT * SROW];
    __shared__ float qs[RT][DK];
    __shared__ float l2inv_s[RT];

    int y = blockIdx.y;
    int set = y >> 4, bh = y & 15;
    const float* Q = set ? Q1 : Q0;
    const float* K = set ? K1 : K0;
    const float* V = set ? V1 : V0;
    const float* gm = set ? g1 : g0;
    float* O = set ? O1 : O0;

    int b = bh >> 3, h = bh & 7;
    int i0 = ((int)gridDim.x - 1 - (int)blockIdx.x) * RT;   // largest-first
    int t = threadIdx.x;
    size_t base = ((size_t)b * SEQ) * DM + (size_t)h * DK;

    {   // load Q tile
        int r = t >> 5, d = t & 31;
        if (t < RT * DK)
            qs[r][d] = qbcast ? Q[(size_t)h * DK + d]
                              : Q[base + (size_t)(i0 + r) * DM + d];
    }
    __syncthreads();

    int njAll = peek ? (i0 + RT) : (i0 + RT - 1);  // >= 7 always
    int njPad = (njAll + 3) & ~3;
    const float scale = 0.17677669529663687f;      // 1/sqrt(32)

    // ---- Phase 1: scores. 4 K rows, q-loop rolled, 1-deep load pipeline.
    #pragma unroll 1
    for (int jb = t; jb < njAll; jb += 1024) {
        int j1 = jb + 256, j2 = jb + 512, j3 = jb + 768;
        int c1 = j1 < njAll ? j1 : jb;
        int c2 = j2 < njAll ? j2 : jb;
        int c3 = j3 < njAll ? j3 : jb;
        const float4* kp0 = (const float4*)(K + base + (size_t)jb * DM);
        const float4* kp1 = (const float4*)(K + base + (size_t)c1 * DM);
        const float4* kp2 = (const float4*)(K + base + (size_t)c2 * DM);
        const float4* kp3 = (const float4*)(K + base + (size_t)c3 * DM);
        float s0[RT], s1[RT], s2[RT], s3[RT];
        #pragma unroll
        for (int r = 0; r < RT; ++r) { s0[r]=0.f; s1[r]=0.f; s2[r]=0.f; s3[r]=0.f; }
        float4 n0 = kp0[0], n1 = kp1[0], n2 = kp2[0], n3 = kp3[0];
        #pragma unroll 1
        for (int q = 0; q < 8; ++q) {
            float4 k0 = n0, k1 = n1, k2 = n2, k3 = n3;
            if (q < 7) {
                n0 = kp0[q + 1]; n1 = kp1[q + 1];
                n2 = kp2[q + 1]; n3 = kp3[q + 1];
            }
            #pragma unroll
            for (int r = 0; r < RT; ++r) {
                float4 qv = *(const float4*)&qs[r][4 * q];
                s0[r] += qv.x*k0.x + qv.y*k0.y + qv.z*k0.z + qv.w*k0.w;
                s1[r] += qv.x*k1.x + qv.y*k1.y + qv.z*k1.z + qv.w*k1.w;
                s2[r] += qv.x*k2.x + qv.y*k2.y + qv.z*k2.z + qv.w*k2.w;
                s3[r] += qv.x*k3.x + qv.y*k3.y + qv.z*k3.z + qv.w*k3.w;
            }
            asm volatile("" ::: "memory");   // qs stays in LDS (anti-LICM)
        }
        {
            int sj = sw(jb);
            #pragma unroll
            for (int r = 0; r < RT; ++r) S[r * SROW + sj] = s0[r] * scale;
        }
        if (j1 < njAll) { int sj = sw(j1);
            #pragma unroll
            for (int r = 0; r < RT; ++r) S[r * SROW + sj] = s1[r] * scale; }
        if (j2 < njAll) { int sj = sw(j2);
            #pragma unroll
            for (int r = 0; r < RT; ++r) S[r * SROW + sj] = s2[r] * scale; }
        if (j3 < njAll) { int sj = sw(j3);
            #pragma unroll
            for (int r = 0; r < RT; ++r) S[r * SROW + sj] = s3[r] * scale; }
    }
    __syncthreads();

    // ---- Phases 2-4: per row, 32 lanes, quad-interleaved
    {
        int r = t >> 5, c = t & 31;
        int i = i0 + r;
        int nj = peek ? (i + 1) : i;          // may be 0 (attn3 row 0)
        float* Sr = S + r * SROW;
        float gamma = -log1pf(__expf(gm[h]));    // -softplus

        // A: max
        float m = -1e30f;
        #pragma unroll 1
        for (int j4 = 4 * c; j4 < nj; j4 += 128) {
            float4 s4 = *(const float4*)&Sr[sw(j4)];
            if (j4 + 0 < nj) m = fmaxf(m, s4.x);
            if (j4 + 1 < nj) m = fmaxf(m, s4.y);
            if (j4 + 2 < nj) m = fmaxf(m, s4.z);
            if (j4 + 3 < nj) m = fmaxf(m, s4.w);
        }
        #pragma unroll
        for (int off = 16; off; off >>= 1) m = fmaxf(m, __shfl_xor(m, off, 32));

        // B: sum exp
        float l = 0.f;
        #pragma unroll 1
        for (int j4 = 4 * c; j4 < nj; j4 += 128) {
            float4 s4 = *(const float4*)&Sr[sw(j4)];
            if (j4 + 0 < nj) l += __expf(s4.x - m);
            if (j4 + 1 < nj) l += __expf(s4.y - m);
            if (j4 + 2 < nj) l += __expf(s4.z - m);
            if (j4 + 3 < nj) l += __expf(s4.w - m);
        }
        #pragma unroll
        for (int off = 16; off; off >>= 1) l += __shfl_xor(l, off, 32);
        float linv = 1.f / l;

        // C: ordered cumsum + decay bias (k-stepped 32-lane scan)
        float m2 = -1e30f;
        float Bc = 0.f;
        #pragma unroll 1
        for (int k = 0; 128 * k < nj; ++k) {
            int j4 = 128 * k + 4 * c;                 // <= 2044: in-bounds read
            float4 s4 = *(const float4*)&Sr[sw(j4)];
            bool v0 = j4 + 0 < nj, v1 = j4 + 1 < nj, v2 = j4 + 2 < nj, v3 = j4 + 3 < nj;
            float e0 = v0 ? __expf(s4.x - m) * linv : 0.f;
            float e1 = v1 ? __expf(s4.y - m) * linv : 0.f;
            float e2 = v2 ? __expf(s4.z - m) * linv : 0.f;
            float e3 = v3 ? __expf(s4.w - m) * linv : 0.f;
            float sig = e0 + e1 + e2 + e3;
            float x = sig;
            #pragma unroll
            for (int off = 1; off < 32; off <<= 1) {
                float yv = __shfl_up(x, off, 32);
                if (c >= off) x += yv;
            }
            float tot = __shfl(x, 31, 32);
            float cum = Bc + (x - sig);
            Bc += tot;
            cum += e0;
            if (v0) { float dist = sqrtf(fmaxf((1.f - cum) * (float)(i - j4 - 0), 0.f));
                      float eff = fminf(fmaxf(__expf(dist * gamma), 1e-5f), 1e5f);
                      s4.x *= eff; m2 = fmaxf(m2, s4.x); } else s4.x = -1e30f;
            cum += e1;
            if (v1) { float dist = sqrtf(fmaxf((1.f - cum) * (float)(i - j4 - 1), 0.f));
                      float eff = fminf(fmaxf(__expf(dist * gamma), 1e-5f), 1e5f);
                      s4.y *= eff; m2 = fmaxf(m2, s4.y); } else s4.y = -1e30f;
            cum += e2;
            if (v2) { float dist = sqrtf(fmaxf((1.f - cum) * (float)(i - j4 - 2), 0.f));
                      float eff = fminf(fmaxf(__expf(dist * gamma), 1e-5f), 1e5f);
                      s4.z *= eff; m2 = fmaxf(m2, s4.z); } else s4.z = -1e30f;
            cum += e3;
            if (v3) { float dist = sqrtf(fmaxf((1.f - cum) * (float)(i - j4 - 3), 0.f));
                      float eff = fminf(fmaxf(__expf(dist * gamma), 1e-5f), 1e5f);
                      s4.w *= eff; m2 = fmaxf(m2, s4.w); } else s4.w = -1e30f;
            *(float4*)&Sr[sw(j4)] = s4;
        }
        #pragma unroll
        for (int off = 16; off; off >>= 1) m2 = fmaxf(m2, __shfl_xor(m2, off, 32));

        // D: p = exp(s2-m2), zero-fill [nj, njPad), sum l2
        float l2 = 0.f;
        #pragma unroll 1
        for (int j4 = 4 * c; j4 < njPad; j4 += 128) {
            float4 s4 = *(const float4*)&Sr[sw(j4)];
            float4 p;
            p.x = (j4 + 0 < nj) ? __expf(s4.x - m2) : 0.f;
            p.y = (j4 + 1 < nj) ? __expf(s4.y - m2) : 0.f;
            p.z = (j4 + 2 < nj) ? __expf(s4.z - m2) : 0.f;
            p.w = (j4 + 3 < nj) ? __expf(s4.w - m2) : 0.f;
            l2 += p.x + p.y + p.z + p.w;
            *(float4*)&Sr[sw(j4)] = p;
        }
        #pragma unroll
        for (int off = 16; off; off >>= 1) l2 += __shfl_xor(l2, off, 32);
        if (c == 0) l2inv_s[r] = (nj > 0) ? (1.f / l2) : 0.f;
    }
    __syncthreads();

    // ---- Phase 5 PV: thread=(jg,d); V loads pipelined 1 iter ahead
    {
        int d = t & 31, jg = t >> 5;
        float acc[RT];
        #pragma unroll
        for (int r = 0; r < RT; ++r) acc[r] = 0.f;
        int j0 = jg * 4;
        float nv0 = 0.f, nv1 = 0.f, nv2 = 0.f, nv3 = 0.f;
        if (j0 < njPad) {
            nv0 = V[base + (size_t)(j0 + 0) * DM + d];
            nv1 = V[base + (size_t)(j0 + 1) * DM + d];
            nv2 = V[base + (size_t)(j0 + 2) * DM + d];
            nv3 = V[base + (size_t)(j0 + 3) * DM + d];
        }
        #pragma unroll 1
        for (int j = j0; j < njPad; j += 32) {
            float v0 = nv0, v1 = nv1, v2 = nv2, v3 = nv3;
            int jn = j + 32;
            if (jn < njPad) {
                nv0 = V[base + (size_t)(jn + 0) * DM + d];
                nv1 = V[base + (size_t)(jn + 1) * DM + d];
                nv2 = V[base + (size_t)(jn + 2) * DM + d];
                nv3 = V[base + (size_t)(jn + 3) * DM + d];
            }
            int sj = sw(j);
            #pragma unroll
            for (int r = 0; r < RT; ++r) {
                float4 p = *(const float4*)&S[r * SROW + sj];
                acc[r] += p.x * v0 + p.y * v1 + p.z * v2 + p.w * v3;
            }
        }
        __syncthreads();          // done reading S -> reuse as scratch
        #pragma unroll
        for (int r = 0; r < RT; ++r)
            S[(jg * RT + r) * 32 + d] = acc[r];    // [jg][r][d]
    }
    __syncthreads();
    {
        int r2 = t >> 5, d = t & 31;
        float sum = 0.f;
        #pragma unroll
        for (int jg = 0; jg < 8; ++jg)
            sum += S[(jg * RT + r2) * 32 + d];
        int ii = i0 + r2;
        int njr = peek ? (ii + 1) : ii;
        O[base + (size_t)ii * DM + d] = (njr > 0) ? sum * l2inv_s[r2] : 0.f;
    }
}

// ---------- small precompute: q3row = know@W3q+b3q; key8 = sigmoid heads ---
__global__ __launch_bounds__(256) void precompute_kernel(
    const float* __restrict__ know,
    const float* __restrict__ W3q, const float* __restrict__ b3q,
    const float* __restrict__ lkW, const float* __restrict__ lkb,
    float* __restrict__ q3row, float* __restrict__ key8)
{
    __shared__ float kn[DM];
    int t = threadIdx.x;
    kn[t] = know[t];
    __syncthreads();
    float acc = b3q[t];
    for (int c = 0; c < DM; ++c) acc += kn[c] * W3q[(size_t)c * DM + t];
    q3row[t] = acc;
    float bk = lkb[t];
    for (int h = 0; h < NH; ++h) {
        float a = bk;
        #pragma unroll
        for (int c = 0; c < DK; ++c) a += kn[h * DK + c] * lkW[(size_t)c * DM + t];
        key8[(size_t)h * DM + t] = 1.f / (1.f + __expf(-a));
    }
}

// ---------- final readout (f32 output) ----------
__global__ __launch_bounds__(256) void readout_kernel(
    const float* __restrict__ h3, const float* __restrict__ qe,
    const float* __restrict__ key8,
    const float* __restrict__ lvW, const float* __restrict__ lvb,
    float* __restrict__ out)
{
    __shared__ float hrow[DM], qrow[DM];
    __shared__ float red[4];
    int n = blockIdx.x, t = threadIdx.x;
    hrow[t] = h3[(size_t)n * DM + t];
    qrow[t] = qe[(size_t)n * DM + t];
    __syncthreads();
    float beta[NH];
    for (int h = 0; h < NH; ++h)
        beta[h] = blockRedSum(key8[(size_t)h * DM + t] * qrow[t], red);
    float bv = lvb[t];
    float vh[NH];
    for (int h = 0; h < NH; ++h) {
        float a = bv;
        #pragma unroll
        for (int c = 0; c < DK; ++c) a += hrow[h * DK + c] * lvW[(size_t)c * DM + t];
        vh[h] = 1.f / (1.f + __expf(-a));
    }
    float mb = beta[0];
    #pragma unroll
    for (int h = 1; h < NH; ++h) mb = fmaxf(mb, beta[h]);
    float se = 0.f, eh[NH];
    #pragma unroll
    for (int h = 0; h < NH; ++h) { eh[h] = __expf(beta[h] - mb); se += eh[h]; }
    float sinv = 1.f / se;
    float o = 0.f;
    #pragma unroll
    for (int h = 0; h < NH; ++h) o += eh[h] * sinv * vh[h];
    out[(size_t)n * DM + t] = o;
}

extern "C" void kernel_launch(void* const* d_in, const int* in_sizes, int n_in,
                              void* d_out, int out_size, void* d_ws, size_t ws_size,
                              hipStream_t stream) {
    (void)in_sizes; (void)n_in; (void)out_size; (void)ws_size;
    const float* q_emb  = (const float*)d_in[0];
    const float* qa_emb = (const float*)d_in[1];
    const float* b1_Wq = (const float*)d_in[2];
    const float* b1_bq = (const float*)d_in[3];
    const float* b1_Wv = (const float*)d_in[4];
    const float* b1_bv = (const float*)d_in[5];
    const float* b1_Wo = (const float*)d_in[6];
    const float* b1_bo = (const float*)d_in[7];
    const float* b1_gam = (const float*)d_in[8];
    const float* b1_lng = (const float*)d_in[9];
    const float* b1_lnb = (const float*)d_in[10];
    const float* b2_Wq = (const float*)d_in[11];
    const float* b2_bq = (const float*)d_in[12];
    const float* b2_Wv = (const float*)d_in[13];
    const float* b2_bv = (const float*)d_in[14];
    const float* b2_Wo = (const float*)d_in[15];
    const float* b2_bo = (const float*)d_in[16];
    const float* b2_gam = (const float*)d_in[17];
    const float* b2_lng = (const float*)d_in[18];
    const float* b2_lnb = (const float*)d_in[19];
    const float* b3_Wq = (const float*)d_in[20];
    const float* b3_bq = (const float*)d_in[21];
    const float* b3_Wk = (const float*)d_in[22];
    const float* b3_bk = (const float*)d_in[23];
    const float* b3_Wv = (const float*)d_in[24];
    const float* b3_bv = (const float*)d_in[25];
    const float* b3_Wo = (const float*)d_in[26];
    const float* b3_bo = (const float*)d_in[27];
    const float* b3_gam = (const float*)d_in[28];
    const float* b3_lng = (const float*)d_in[29];
    const float* b3_lnb = (const float*)d_in[30];
    const float* know  = (const float*)d_in[31];
    const float* lk_W  = (const float*)d_in[32];
    const float* lk_b  = (const float*)d_in[33];
    const float* lv_W  = (const float*)d_in[34];
    const float* lv_b  = (const float*)d_in[35];

    const size_t SLAB = (size_t)ROWS * DM;  // 1,048,576 floats = 4 MB
    float* A1 = (float*)d_ws;
    float* B1 = A1 + SLAB;
    float* A2 = B1 + SLAB;
    float* B2 = A2 + SLAB;
    float* C1 = B2 + SLAB;
    float* C2 = C1 + SLAB;
    float* q3row = C2 + SLAB;         // 256
    float* key8  = q3row + DM;        // 8*256

    dim3 blk(256);
    dim3 agrid2(SEQ / RT, 32);        // dual-set attention
    dim3 agrid1(SEQ / RT, 16);        // single-set attention
    dim3 rgrid(ROWS);

    precompute_kernel<<<dim3(1), blk, 0, stream>>>(know, b3_Wq, b3_bq, lk_W, lk_b, q3row, key8);

    // ---- blocks 1+2 QKV projections (4 GEMMs, one launch) ----
    gemm4_kernel<<<dim3(ROWS/GR, 4), blk, 0, stream>>>(
        q_emb,  b1_Wq, b1_bq, A1,
        q_emb,  b1_Wv, b1_bv, B1,
        qa_emb, b2_Wq, b2_bq, A2,
        qa_emb, b2_Wv, b2_bv, B2);

    // ---- blocks 1+2 attention (one dual-set launch) ----
    attn_tile_kernel<<<agrid2, blk, 0, stream>>>(
        A1, A1, B1, b1_gam, C1,
        A2, A2, B2, b2_gam, C2, 1, 0);

    // ---- output projections + residual + LN (fused) -> hq, ha ----
    gemm_ln2_kernel<<<dim3(ROWS/GR, 2), blk, 0, stream>>>(
        C1, b1_Wo, b1_bo, q_emb,  b1_lng, b1_lnb, B1, 0,
        C2, b2_Wo, b2_bo, qa_emb, b2_lng, b2_lnb, B2, 0);

    // ---- block 3: k3 = hq@W3k, v3 = ha@W3v ----
    gemm4_kernel<<<dim3(ROWS/GR, 2), blk, 0, stream>>>(
        B1, b3_Wk, b3_bk, A1,
        B2, b3_Wv, b3_bv, A2,
        B1, b3_Wk, b3_bk, A1,   // unused
        B1, b3_Wk, b3_bk, A1);

    attn_tile_kernel<<<agrid1, blk, 0, stream>>>(
        q3row, A1, A2, b3_gam, C1,
        q3row, A1, A2, b3_gam, C1, 0, 1);

    // ---- y3 + know-residual + LN (fused) -> h3 ----
    gemm_ln2_kernel<<<dim3(ROWS/GR, 1), blk, 0, stream>>>(
        C1, b3_Wo, b3_bo, know, b3_lng, b3_lnb, A1, 1,
        C1, b3_Wo, b3_bo, know, b3_lng, b3_lnb, A1, 1);

    readout_kernel<<<rgrid, blk, 0, stream>>>(A1, q_emb, key8, lv_W, lv_b,
                                              (float*)d_out);
}

// Round 13
// 1030.132 us; speedup vs baseline: 1.8631x; 1.0830x over previous
//
#include <hip/hip_runtime.h>
#include <hip/hip_bf16.h>

#define DM 256
#define NH 8
#define DK 32
#define BSZ 2
#define SEQ 2048
#define ROWS (BSZ*SEQ)   // 4096
#define RT 8             // query rows per attention tile
#define SROW 2304        // phys row stride; swizzle phys = j + 4*(j>>5), max 2299
#define GR 8             // gemm rows per block

static __device__ __forceinline__ int sw(int j) { return j + ((j >> 5) << 2); }

// ---------- reduction helpers ----------
static __device__ __forceinline__ float waveRedSum(float v) {
    #pragma unroll
    for (int off = 32; off > 0; off >>= 1) v += __shfl_down(v, off, 64);
    return v;
}

// ---------- batched GEMM: up to 4 sets, 8 rows/block, W-pipelined ----------
__global__ __launch_bounds__(256) void gemm4_kernel(
    const float* __restrict__ X0, const float* __restrict__ W0, const float* __restrict__ B0, float* __restrict__ Y0,
    const float* __restrict__ X1, const float* __restrict__ W1, const float* __restrict__ B1, float* __restrict__ Y1,
    const float* __restrict__ X2, const float* __restrict__ W2, const float* __restrict__ B2, float* __restrict__ Y2,
    const float* __restrict__ X3, const float* __restrict__ W3, const float* __restrict__ B3, float* __restrict__ Y3)
{
    const float *X, *W, *Bb; float* Y;
    int s = blockIdx.y;
    if (s == 0)      { X = X0; W = W0; Bb = B0; Y = Y0; }
    else if (s == 1) { X = X1; W = W1; Bb = B1; Y = Y1; }
    else if (s == 2) { X = X2; W = W2; Bb = B2; Y = Y2; }
    else             { X = X3; W = W3; Bb = B3; Y = Y3; }

    __shared__ float xl[GR][DM];
    int t = threadIdx.x;
    int r0 = blockIdx.x * GR;
    #pragma unroll
    for (int k = 0; k < GR; ++k) xl[k][t] = X[(size_t)(r0 + k) * DM + t];
    __syncthreads();
    float acc[GR];
    #pragma unroll
    for (int r = 0; r < GR; ++r) acc[r] = 0.f;
    float w0 = W[t], w1 = W[DM + t], w2 = W[2 * DM + t], w3 = W[3 * DM + t];
    #pragma unroll 1
    for (int k = 0; k < DM; k += 4) {
        float c0 = w0, c1 = w1, c2 = w2, c3 = w3;
        if (k + 4 < DM) {
            w0 = W[(size_t)(k + 4) * DM + t];
            w1 = W[(size_t)(k + 5) * DM + t];
            w2 = W[(size_t)(k + 6) * DM + t];
            w3 = W[(size_t)(k + 7) * DM + t];
        }
        #pragma unroll
        for (int r = 0; r < GR; ++r) {
            float4 xv = *(const float4*)&xl[r][k];
            acc[r] += xv.x * c0 + xv.y * c1 + xv.z * c2 + xv.w * c3;
        }
    }
    float bb = Bb[t];
    #pragma unroll
    for (int r = 0; r < GR; ++r) Y[(size_t)(r0 + r) * DM + t] = acc[r] + bb;
}

// ---------- GEMM + residual + LayerNorm fused (2 sets), 8 rows/block -------
__global__ __launch_bounds__(256) void gemm_ln2_kernel(
    const float* __restrict__ X0, const float* __restrict__ W0, const float* __restrict__ B0,
    const float* __restrict__ R0, const float* __restrict__ G0, const float* __restrict__ L0,
    float* __restrict__ Y0, int bc0,
    const float* __restrict__ X1, const float* __restrict__ W1, const float* __restrict__ B1,
    const float* __restrict__ R1, const float* __restrict__ G1, const float* __restrict__ L1,
    float* __restrict__ Y1, int bc1)
{
    const float *X, *W, *Bb, *R, *G, *L; float* Y; int bc;
    if (blockIdx.y == 0) { X=X0; W=W0; Bb=B0; R=R0; G=G0; L=L0; Y=Y0; bc=bc0; }
    else                 { X=X1; W=W1; Bb=B1; R=R1; G=G1; L=L1; Y=Y1; bc=bc1; }

    __shared__ float xl[GR][DM];
    __shared__ float mn[GR], rv[GR];
    int t = threadIdx.x;
    int r0 = blockIdx.x * GR;
    #pragma unroll
    for (int k = 0; k < GR; ++k) xl[k][t] = X[(size_t)(r0 + k) * DM + t];
    __syncthreads();
    float acc[GR];
    #pragma unroll
    for (int r = 0; r < GR; ++r) acc[r] = 0.f;
    float w0 = W[t], w1 = W[DM + t], w2 = W[2 * DM + t], w3 = W[3 * DM + t];
    #pragma unroll 1
    for (int k = 0; k < DM; k += 4) {
        float c0 = w0, c1 = w1, c2 = w2, c3 = w3;
        if (k + 4 < DM) {
            w0 = W[(size_t)(k + 4) * DM + t];
            w1 = W[(size_t)(k + 5) * DM + t];
            w2 = W[(size_t)(k + 6) * DM + t];
            w3 = W[(size_t)(k + 7) * DM + t];
        }
        #pragma unroll
        for (int r = 0; r < GR; ++r) {
            float4 xv = *(const float4*)&xl[r][k];
            acc[r] += xv.x * c0 + xv.y * c1 + xv.z * c2 + xv.w * c3;
        }
    }
    float bb = Bb[t];
    __syncthreads();          // all readers of xl done before overwrite
    #pragma unroll
    for (int r = 0; r < GR; ++r) {
        float res = bc ? R[t] : R[(size_t)(r0 + r) * DM + t];
        xl[r][t] = acc[r] + bb + res;
    }
    __syncthreads();
    {   // 32 threads per row: mean & var
        int r = t >> 5, c32 = t & 31;
        float part = 0.f;
        #pragma unroll
        for (int c = 0; c < 8; ++c) part += xl[r][c32 * 8 + c];
        #pragma unroll
        for (int off = 16; off; off >>= 1) part += __shfl_xor(part, off, 32);
        float mean = part * (1.f / DM);
        float vp = 0.f;
        #pragma unroll
        for (int c = 0; c < 8; ++c) {
            float d = xl[r][c32 * 8 + c] - mean;
            vp += d * d;
        }
        #pragma unroll
        for (int off = 16; off; off >>= 1) vp += __shfl_xor(vp, off, 32);
        if (c32 == 0) { mn[r] = mean; rv[r] = rsqrtf(vp * (1.f / DM) + 1e-5f); }
    }
    __syncthreads();
    float gg = G[t], ll = L[t];
    #pragma unroll
    for (int r = 0; r < GR; ++r)
        Y[(size_t)(r0 + r) * DM + t] = (xl[r][t] - mn[r]) * rv[r] * gg + ll;
}

// ---------- tiled attention with distance-decay bias ----------
// RT=8, dual-set, largest-first. r10 phase-1 (no manual pipeline: r11/r12
// both regressed). No-max softmax (|s|<~20 by construction) folds 4 passes
// into 2. qbcast: scores identical across tile rows -> compute once.
__global__ __launch_bounds__(256) void attn_tile_kernel(
    const float* __restrict__ Q0, const float* __restrict__ K0, const float* __restrict__ V0,
    const float* __restrict__ g0, float* __restrict__ O0,
    const float* __restrict__ Q1, const float* __restrict__ K1, const float* __restrict__ V1,
    const float* __restrict__ g1, float* __restrict__ O1,
    int peek, int qbcast)
{
    __shared__ __align__(16) float S[RT * SROW];
    __shared__ float qs[RT][DK];
    __shared__ float l2inv_s[RT];

    int y = blockIdx.y;
    int set = y >> 4, bh = y & 15;
    const float* Q = set ? Q1 : Q0;
    const float* K = set ? K1 : K0;
    const float* V = set ? V1 : V0;
    const float* gm = set ? g1 : g0;
    float* O = set ? O1 : O0;

    int b = bh >> 3, h = bh & 7;
    int i0 = ((int)gridDim.x - 1 - (int)blockIdx.x) * RT;   // largest-first
    int t = threadIdx.x;
    size_t base = ((size_t)b * SEQ) * DM + (size_t)h * DK;

    {   // load Q tile
        int r = t >> 5, d = t & 31;
        if (t < RT * DK)
            qs[r][d] = qbcast ? Q[(size_t)h * DK + d]
                              : Q[base + (size_t)(i0 + r) * DM + d];
    }
    __syncthreads();

    int njAll = peek ? (i0 + RT) : (i0 + RT - 1);  // >= 7 always
    int njPad = (njAll + 3) & ~3;
    const float scale = 0.17677669529663687f;      // 1/sqrt(32)

    // ---- Phase 1: scores (r10 form).
    if (qbcast) {
        // all tile rows share the same q -> one dot product per j
        #pragma unroll 1
        for (int jb = t; jb < njAll; jb += 1024) {
            int j1 = jb + 256, j2 = jb + 512, j3 = jb + 768;
            int c1 = j1 < njAll ? j1 : jb;
            int c2 = j2 < njAll ? j2 : jb;
            int c3 = j3 < njAll ? j3 : jb;
            const float4* kp0 = (const float4*)(K + base + (size_t)jb * DM);
            const float4* kp1 = (const float4*)(K + base + (size_t)c1 * DM);
            const float4* kp2 = (const float4*)(K + base + (size_t)c2 * DM);
            const float4* kp3 = (const float4*)(K + base + (size_t)c3 * DM);
            float s0 = 0.f, s1 = 0.f, s2 = 0.f, s3 = 0.f;
            #pragma unroll 1
            for (int q = 0; q < 8; ++q) {
                float4 k0 = kp0[q], k1 = kp1[q], k2 = kp2[q], k3 = kp3[q];
                float4 qv = *(const float4*)&qs[0][4 * q];
                s0 += qv.x*k0.x + qv.y*k0.y + qv.z*k0.z + qv.w*k0.w;
                s1 += qv.x*k1.x + qv.y*k1.y + qv.z*k1.z + qv.w*k1.w;
                s2 += qv.x*k2.x + qv.y*k2.y + qv.z*k2.z + qv.w*k2.w;
                s3 += qv.x*k3.x + qv.y*k3.y + qv.z*k3.z + qv.w*k3.w;
                asm volatile("" ::: "memory");
            }
            {
                int sj = sw(jb);
                #pragma unroll
                for (int r = 0; r < RT; ++r) S[r * SROW + sj] = s0 * scale;
            }
            if (j1 < njAll) { int sj = sw(j1);
                #pragma unroll
                for (int r = 0; r < RT; ++r) S[r * SROW + sj] = s1 * scale; }
            if (j2 < njAll) { int sj = sw(j2);
                #pragma unroll
                for (int r = 0; r < RT; ++r) S[r * SROW + sj] = s2 * scale; }
            if (j3 < njAll) { int sj = sw(j3);
                #pragma unroll
                for (int r = 0; r < RT; ++r) S[r * SROW + sj] = s3 * scale; }
        }
    } else {
        #pragma unroll 1
        for (int jb = t; jb < njAll; jb += 1024) {
            int j1 = jb + 256, j2 = jb + 512, j3 = jb + 768;
            int c1 = j1 < njAll ? j1 : jb;
            int c2 = j2 < njAll ? j2 : jb;
            int c3 = j3 < njAll ? j3 : jb;
            const float4* kp0 = (const float4*)(K + base + (size_t)jb * DM);
            const float4* kp1 = (const float4*)(K + base + (size_t)c1 * DM);
            const float4* kp2 = (const float4*)(K + base + (size_t)c2 * DM);
            const float4* kp3 = (const float4*)(K + base + (size_t)c3 * DM);
            float s0[RT], s1[RT], s2[RT], s3[RT];
            #pragma unroll
            for (int r = 0; r < RT; ++r) { s0[r]=0.f; s1[r]=0.f; s2[r]=0.f; s3[r]=0.f; }
            #pragma unroll 1
            for (int q = 0; q < 8; ++q) {
                float4 k0 = kp0[q], k1 = kp1[q], k2 = kp2[q], k3 = kp3[q];
                #pragma unroll
                for (int r = 0; r < RT; ++r) {
                    float4 qv = *(const float4*)&qs[r][4 * q];
                    s0[r] += qv.x*k0.x + qv.y*k0.y + qv.z*k0.z + qv.w*k0.w;
                    s1[r] += qv.x*k1.x + qv.y*k1.y + qv.z*k1.z + qv.w*k1.w;
                    s2[r] += qv.x*k2.x + qv.y*k2.y + qv.z*k2.z + qv.w*k2.w;
                    s3[r] += qv.x*k3.x + qv.y*k3.y + qv.z*k3.z + qv.w*k3.w;
                }
                asm volatile("" ::: "memory");   // qs stays in LDS (anti-LICM)
            }
            {
                int sj = sw(jb);
                #pragma unroll
                for (int r = 0; r < RT; ++r) S[r * SROW + sj] = s0[r] * scale;
            }
            if (j1 < njAll) { int sj = sw(j1);
                #pragma unroll
                for (int r = 0; r < RT; ++r) S[r * SROW + sj] = s1[r] * scale; }
            if (j2 < njAll) { int sj = sw(j2);
                #pragma unroll
                for (int r = 0; r < RT; ++r) S[r * SROW + sj] = s2[r] * scale; }
            if (j3 < njAll) { int sj = sw(j3);
                #pragma unroll
                for (int r = 0; r < RT; ++r) S[r * SROW + sj] = s3[r] * scale; }
        }
    }
    __syncthreads();

    // ---- Phases 2-3 (no-max softmax): B = sum exp; C = scan+bias+p, l2
    {
        int r = t >> 5, c = t & 31;
        int i = i0 + r;
        int nj = peek ? (i + 1) : i;          // may be 0 (attn3 row 0)
        float* Sr = S + r * SROW;
        float gamma = -log1pf(__expf(gm[h]));    // -softplus

        // B: l = sum exp(s)   (scores bounded; no max-shift needed)
        float l = 0.f;
        #pragma unroll 1
        for (int j4 = 4 * c; j4 < nj; j4 += 128) {
            float4 s4 = *(const float4*)&Sr[sw(j4)];
            if (j4 + 0 < nj) l += __expf(s4.x);
            if (j4 + 1 < nj) l += __expf(s4.y);
            if (j4 + 2 < nj) l += __expf(s4.z);
            if (j4 + 3 < nj) l += __expf(s4.w);
        }
        #pragma unroll
        for (int off = 16; off; off >>= 1) l += __shfl_xor(l, off, 32);
        float linv = 1.f / l;

        // C: ordered cumsum + decay bias + p=exp(s*eff), accumulate l2
        float l2 = 0.f;
        float Bc = 0.f;
        #pragma unroll 1
        for (int k = 0; 128 * k < njPad; ++k) {
            int j4 = 128 * k + 4 * c;                 // <= 2044: in-bounds read
            float4 s4 = *(const float4*)&Sr[sw(j4)];
            bool v0 = j4 + 0 < nj, v1 = j4 + 1 < nj, v2 = j4 + 2 < nj, v3 = j4 + 3 < nj;
            float e0 = v0 ? __expf(s4.x) * linv : 0.f;
            float e1 = v1 ? __expf(s4.y) * linv : 0.f;
            float e2 = v2 ? __expf(s4.z) * linv : 0.f;
            float e3 = v3 ? __expf(s4.w) * linv : 0.f;
            float sig = e0 + e1 + e2 + e3;
            float x = sig;
            #pragma unroll
            for (int off = 1; off < 32; off <<= 1) {
                float yv = __shfl_up(x, off, 32);
                if (c >= off) x += yv;
            }
            float tot = __shfl(x, 31, 32);
            float cum = Bc + (x - sig);
            Bc += tot;
            float4 p;
            cum += e0;
            if (v0) { float dist = sqrtf(fmaxf((1.f - cum) * (float)(i - j4 - 0), 0.f));
                      float eff = fminf(fmaxf(__expf(dist * gamma), 1e-5f), 1e5f);
                      p.x = __expf(s4.x * eff); l2 += p.x; } else p.x = 0.f;
            cum += e1;
            if (v1) { float dist = sqrtf(fmaxf((1.f - cum) * (float)(i - j4 - 1), 0.f));
                      float eff = fminf(fmaxf(__expf(dist * gamma), 1e-5f), 1e5f);
                      p.y = __expf(s4.y * eff); l2 += p.y; } else p.y = 0.f;
            cum += e2;
            if (v2) { float dist = sqrtf(fmaxf((1.f - cum) * (float)(i - j4 - 2), 0.f));
                      float eff = fminf(fmaxf(__expf(dist * gamma), 1e-5f), 1e5f);
                      p.z = __expf(s4.z * eff); l2 += p.z; } else p.z = 0.f;
            cum += e3;
            if (v3) { float dist = sqrtf(fmaxf((1.f - cum) * (float)(i - j4 - 3), 0.f));
                      float eff = fminf(fmaxf(__expf(dist * gamma), 1e-5f), 1e5f);
                      p.w = __expf(s4.w * eff); l2 += p.w; } else p.w = 0.f;
            if (j4 < njPad) *(float4*)&Sr[sw(j4)] = p;
        }
        #pragma unroll
        for (int off = 16; off; off >>= 1) l2 += __shfl_xor(l2, off, 32);
        if (c == 0) l2inv_s[r] = (nj > 0) ? (1.f / l2) : 0.f;
    }
    __syncthreads();

    // ---- Phase 5 PV: thread=(jg,d); quad b128 P reads, coalesced V
    {
        int d = t & 31, jg = t >> 5;
        float acc[RT];
        #pragma unroll
        for (int r = 0; r < RT; ++r) acc[r] = 0.f;
        #pragma unroll 1
        for (int j = jg * 4; j < njPad; j += 32) {
            float v0 = V[base + (size_t)(j + 0) * DM + d];
            float v1 = V[base + (size_t)(j + 1) * DM + d];
            float v2 = V[base + (size_t)(j + 2) * DM + d];
            float v3 = V[base + (size_t)(j + 3) * DM + d];
            int sj = sw(j);
            #pragma unroll
            for (int r = 0; r < RT; ++r) {
                float4 p = *(const float4*)&S[r * SROW + sj];
                acc[r] += p.x * v0 + p.y * v1 + p.z * v2 + p.w * v3;
            }
        }
        __syncthreads();          // done reading S -> reuse as scratch
        #pragma unroll
        for (int r = 0; r < RT; ++r)
            S[(jg * RT + r) * 32 + d] = acc[r];    // [jg][r][d]
    }
    __syncthreads();
    {
        int r2 = t >> 5, d = t & 31;
        float sum = 0.f;
        #pragma unroll
        for (int jg = 0; jg < 8; ++jg)
            sum += S[(jg * RT + r2) * 32 + d];
        int ii = i0 + r2;
        int njr = peek ? (ii + 1) : ii;
        O[base + (size_t)ii * DM + d] = (njr > 0) ? sum * l2inv_s[r2] : 0.f;
    }
}

// ---------- small precompute: q3row = know@W3q+b3q; key8 = sigmoid heads ---
__global__ __launch_bounds__(256) void precompute_kernel(
    const float* __restrict__ know,
    const float* __restrict__ W3q, const float* __restrict__ b3q,
    const float* __restrict__ lkW, const float* __restrict__ lkb,
    float* __restrict__ q3row, float* __restrict__ key8)
{
    __shared__ float kn[DM];
    int t = threadIdx.x;
    kn[t] = know[t];
    __syncthreads();
    float acc = b3q[t];
    for (int c = 0; c < DM; ++c) acc += kn[c] * W3q[(size_t)c * DM + t];
    q3row[t] = acc;
    float bk = lkb[t];
    for (int h = 0; h < NH; ++h) {
        float a = bk;
        #pragma unroll
        for (int c = 0; c < DK; ++c) a += kn[h * DK + c] * lkW[(size_t)c * DM + t];
        key8[(size_t)h * DM + t] = 1.f / (1.f + __expf(-a));
    }
}

// ---------- final readout (f32 output), single-barrier beta reduction ------
__global__ __launch_bounds__(256) void readout_kernel(
    const float* __restrict__ h3, const float* __restrict__ qe,
    const float* __restrict__ key8,
    const float* __restrict__ lvW, const float* __restrict__ lvb,
    float* __restrict__ out)
{
    __shared__ float hrow[DM], qrow[DM];
    __shared__ float red8[4][NH];
    int n = blockIdx.x, t = threadIdx.x;
    int lane = t & 63, wid = t >> 6;
    hrow[t] = h3[(size_t)n * DM + t];
    qrow[t] = qe[(size_t)n * DM + t];
    __syncthreads();
    float ph[NH];
    #pragma unroll
    for (int h = 0; h < NH; ++h) {
        float v = key8[(size_t)h * DM + t] * qrow[t];
        v = waveRedSum(v);
        ph[h] = v;
    }
    if (lane == 0) {
        #pragma unroll
        for (int h = 0; h < NH; ++h) red8[wid][h] = ph[h];
    }
    __syncthreads();
    float beta[NH];
    #pragma unroll
    for (int h = 0; h < NH; ++h)
        beta[h] = red8[0][h] + red8[1][h] + red8[2][h] + red8[3][h];
    float bv = lvb[t];
    float vh[NH];
    for (int h = 0; h < NH; ++h) {
        float a = bv;
        #pragma unroll
        for (int c = 0; c < DK; ++c) a += hrow[h * DK + c] * lvW[(size_t)c * DM + t];
        vh[h] = 1.f / (1.f + __expf(-a));
    }
    float mb = beta[0];
    #pragma unroll
    for (int h = 1; h < NH; ++h) mb = fmaxf(mb, beta[h]);
    float se = 0.f, eh[NH];
    #pragma unroll
    for (int h = 0; h < NH; ++h) { eh[h] = __expf(beta[h] - mb); se += eh[h]; }
    float sinv = 1.f / se;
    float o = 0.f;
    #pragma unroll
    for (int h = 0; h < NH; ++h) o += eh[h] * sinv * vh[h];
    out[(size_t)n * DM + t] = o;
}

extern "C" void kernel_launch(void* const* d_in, const int* in_sizes, int n_in,
                              void* d_out, int out_size, void* d_ws, size_t ws_size,
                              hipStream_t stream) {
    (void)in_sizes; (void)n_in; (void)out_size; (void)ws_size;
    const float* q_emb  = (const float*)d_in[0];
    const float* qa_emb = (const float*)d_in[1];
    const float* b1_Wq = (const float*)d_in[2];
    const float* b1_bq = (const float*)d_in[3];
    const float* b1_Wv = (const float*)d_in[4];
    const float* b1_bv = (const float*)d_in[5];
    const float* b1_Wo = (const float*)d_in[6];
    const float* b1_bo = (const float*)d_in[7];
    const float* b1_gam = (const float*)d_in[8];
    const float* b1_lng = (const float*)d_in[9];
    const float* b1_lnb = (const float*)d_in[10];
    const float* b2_Wq = (const float*)d_in[11];
    const float* b2_bq = (const float*)d_in[12];
    const float* b2_Wv = (const float*)d_in[13];
    const float* b2_bv = (const float*)d_in[14];
    const float* b2_Wo = (const float*)d_in[15];
    const float* b2_bo = (const float*)d_in[16];
    const float* b2_gam = (const float*)d_in[17];
    const float* b2_lng = (const float*)d_in[18];
    const float* b2_lnb = (const float*)d_in[19];
    const float* b3_Wq = (const float*)d_in[20];
    const float* b3_bq = (const float*)d_in[21];
    const float* b3_Wk = (const float*)d_in[22];
    const float* b3_bk = (const float*)d_in[23];
    const float* b3_Wv = (const float*)d_in[24];
    const float* b3_bv = (const float*)d_in[25];
    const float* b3_Wo = (const float*)d_in[26];
    const float* b3_bo = (const float*)d_in[27];
    const float* b3_gam = (const float*)d_in[28];
    const float* b3_lng = (const float*)d_in[29];
    const float* b3_lnb = (const float*)d_in[30];
    const float* know  = (const float*)d_in[31];
    const float* lk_W  = (const float*)d_in[32];
    const float* lk_b  = (const float*)d_in[33];
    const float* lv_W  = (const float*)d_in[34];
    const float* lv_b  = (const float*)d_in[35];

    const size_t SLAB = (size_t)ROWS * DM;  // 1,048,576 floats = 4 MB
    float* A1 = (float*)d_ws;
    float* B1 = A1 + SLAB;
    float* A2 = B1 + SLAB;
    float* B2 = A2 + SLAB;
    float* C1 = B2 + SLAB;
    float* C2 = C1 + SLAB;
    float* q3row = C2 + SLAB;         // 256
    float* key8  = q3row + DM;        // 8*256

    dim3 blk(256);
    dim3 agrid2(SEQ / RT, 32);        // dual-set attention
    dim3 agrid1(SEQ / RT, 16);        // single-set attention
    dim3 rgrid(ROWS);

    precompute_kernel<<<dim3(1), blk, 0, stream>>>(know, b3_Wq, b3_bq, lk_W, lk_b, q3row, key8);

    // ---- blocks 1+2 QKV projections (4 GEMMs, one launch) ----
    gemm4_kernel<<<dim3(ROWS/GR, 4), blk, 0, stream>>>(
        q_emb,  b1_Wq, b1_bq, A1,
        q_emb,  b1_Wv, b1_bv, B1,
        qa_emb, b2_Wq, b2_bq, A2,
        qa_emb, b2_Wv, b2_bv, B2);

    // ---- blocks 1+2 attention (one dual-set launch) ----
    attn_tile_kernel<<<agrid2, blk, 0, stream>>>(
        A1, A1, B1, b1_gam, C1,
        A2, A2, B2, b2_gam, C2, 1, 0);

    // ---- output projections + residual + LN (fused) -> hq, ha ----
    gemm_ln2_kernel<<<dim3(ROWS/GR, 2), blk, 0, stream>>>(
        C1, b1_Wo, b1_bo, q_emb,  b1_lng, b1_lnb, B1, 0,
        C2, b2_Wo, b2_bo, qa_emb, b2_lng, b2_lnb, B2, 0);

    // ---- block 3: k3 = hq@W3k, v3 = ha@W3v ----
    gemm4_kernel<<<dim3(ROWS/GR, 2), blk, 0, stream>>>(
        B1, b3_Wk, b3_bk, A1,
        B2, b3_Wv, b3_bv, A2,
        B1, b3_Wk, b3_bk, A1,   // unused
        B1, b3_Wk, b3_bk, A1);

    attn_tile_kernel<<<agrid1, blk, 0, stream>>>(
        q3row, A1, A2, b3_gam, C1,
        q3row, A1, A2, b3_gam, C1, 0, 1);

    // ---- y3 + know-residual + LN (fused) -> h3 ----
    gemm_ln2_kernel<<<dim3(ROWS/GR, 1), blk, 0, stream>>>(
        C1, b3_Wo, b3_bo, know, b3_lng, b3_lnb, A1, 1,
        C1, b3_Wo, b3_bo, know, b3_lng, b3_lnb, A1, 1);

    readout_kernel<<<rgrid, blk, 0, stream>>>(A1, q_emb, key8, lv_W, lv_b,
                                              (float*)d_out);
}